// Round 5
// baseline (18.896 us; speedup 1.0000x reference)
//
#include <hip/hip_runtime.h>

// out[b,i,h] = m_i * (1/denom_b) * sum_{j valid} sigmoid(zc[b,i,h] + zy[b,j,h])
// zc = z@Wc^T+bc, zy = z@Wy^T+by.
// sigmoid(a+b) = 1/(1+e^{-a}e^{-b}); E=e^{-zc} (regs), F=e^{-zy} (LDS).
// COMPACTION: only ~70% of rows are valid. Invalid i -> output 0 (skip all
// compute); invalid j -> skipped via compacted F (valid j's F stored densely
// at prefix-popcount positions, padded with 1e8 sentinel to a multiple of 4).
// Stage B: runtime quad loop (nq=ceil(nvalid/4)), 4-way rational combine:
// 1/t0+1/t1+1/t2+1/t3 = (sum triple products)/(t0t1t2t3) -> 1 v_rcp per 4 j.

#define LOG2E 1.4426950408889634f

constexpr int NV = 48;
constexpr int H  = 32;
constexpr int BLOCK = 512;      // 8 waves; thread = (i0 in 0..15, h in 0..31)
constexpr int WPAD = 36;        // padded W row stride (floats), 16B-aligned rows
constexpr int FROWS = 52;       // 48 + 4 sentinel pad rows
constexpr float F_INV = 1.0e8f; // sentinel: contribution ~1e-8 per term

__global__ __launch_bounds__(BLOCK, 4)
void OptLinker_attn_kernel(const float* __restrict__ z,
                           const float* __restrict__ Wc,
                           const float* __restrict__ bc,
                           const float* __restrict__ Wy,
                           const float* __restrict__ by,
                           const int*   __restrict__ mask,
                           float* __restrict__ out)
{
    __shared__ float z_s[NV * H];        // 6 KB
    __shared__ float F_s[FROWS * H];     // 6.5 KB compacted e^{-zy} + pads
    __shared__ float wc_s[H * WPAD];     // 4.5 KB
    __shared__ float wy_s[H * WPAD];     // 4.5 KB
    __shared__ int   validIdx[NV];       // compacted slot -> original row

    const int b   = blockIdx.x;
    const int tid = threadIdx.x;
    const int h   = tid & 31;            // lane's H column
    const int i0  = tid >> 5;            // 0..15 compacted-slot group

    // ---- mask ballot (identical in every wave) + bias prefetch ----
    const int lane = tid & 63;
    const int mv = (lane < NV) ? mask[b * NV + lane] : 0;
    const float bcv = bc[h], byv = by[h];

    // ---- z tile -> LDS (float4, coalesced) ----
    const float4* zb4 = (const float4*)(z + (size_t)b * (NV * H));
    if (tid < (NV * H) / 4) ((float4*)z_s)[tid] = zb4[tid];

    // ---- W -> LDS, coalesced, one float4 per thread ----
    {
        const int q = tid & 255;
        const float4 v = (tid < 256) ? ((const float4*)Wc)[q]
                                     : ((const float4*)Wy)[q];
        float* dst = (tid < 256 ? wc_s : wy_s) + (q >> 3) * WPAD + (q & 7) * 4;
        *(float4*)dst = v;
    }

    const unsigned long long bits = __ballot(mv != 0);
    const int nvalid = __popcll(bits);

    // ---- wave 0 builds compacted index list (init pads to row 0) ----
    if (tid < NV) validIdx[tid] = 0;
    if (tid < 64 && mv != 0) {
        const int pos = __popcll(bits & ((1ull << lane) - 1ull));
        validIdx[pos] = lane;            // same wave: ds ops ordered, no race
    }
    // sentinel pad rows [nvalid, nvalid+3]
    if (tid < 4 * H) {
        const int r = nvalid + (tid >> 5);
        if (r < FROWS) F_s[r * H + h] = F_INV;
    }

    __syncthreads();   // z_s, W, validIdx ready

    // ---- W row h -> registers via ds_read_b128 ----
    float4 wc_r[8], wy_r[8];
    {
        const float* wrc = wc_s + h * WPAD;
        const float* wry = wy_s + h * WPAD;
        #pragma unroll
        for (int q = 0; q < 8; ++q) {
            wc_r[q] = *(const float4*)(wrc + q * 4);
            wy_r[q] = *(const float4*)(wry + q * 4);
        }
    }

    // ---- stage A for one compacted slot: E out, F_s[slot] written ----
    auto stageA = [&](int v, float& Eout) {
        const int r = validIdx[v];                   // broadcast ds_read
        float accC = bcv, accY = byv;
        const float4* zr = (const float4*)(z_s + r * H);
        #pragma unroll
        for (int q = 0; q < 8; ++q) {
            const float4 zv = zr[q];                 // broadcast ds_read_b128
            accC = fmaf(zv.x, wc_r[q].x, accC);
            accC = fmaf(zv.y, wc_r[q].y, accC);
            accC = fmaf(zv.z, wc_r[q].z, accC);
            accC = fmaf(zv.w, wc_r[q].w, accC);
            accY = fmaf(zv.x, wy_r[q].x, accY);
            accY = fmaf(zv.y, wy_r[q].y, accY);
            accY = fmaf(zv.z, wy_r[q].z, accY);
            accY = fmaf(zv.w, wy_r[q].w, accY);
        }
        Eout = __builtin_amdgcn_exp2f(-accC * LOG2E);            // e^{-zc}
        if (v < nvalid)
            F_s[v * H + h] = __builtin_amdgcn_exp2f(-accY * LOG2E); // e^{-zy}
    };

    float E0, E1, E2 = 0.f;
    const bool hasRow2 = (i0 + 32) < nvalid;         // wave-uniform for 7/8 waves
    stageA(i0, E0);
    stageA(i0 + 16, E1);
    if (hasRow2) stageA(i0 + 32, E2);

    __syncthreads();   // F_s (compacted + pads) ready

    // ---- stage B: quad loop over compacted j, 4-way rational combine ----
    const int nq = (nvalid + 3) >> 2;
    float acc0 = 0.f, acc1 = 0.f, acc2 = 0.f;
    #pragma unroll 2
    for (int q = 0; q < nq; ++q) {
        const float f0 = F_s[(4 * q + 0) * H + h];   // conflict-free broadcast
        const float f1 = F_s[(4 * q + 1) * H + h];
        const float f2 = F_s[(4 * q + 2) * H + h];
        const float f3 = F_s[(4 * q + 3) * H + h];
        {
            const float t0 = fmaf(E0, f0, 1.0f), t1 = fmaf(E0, f1, 1.0f);
            const float t2 = fmaf(E0, f2, 1.0f), t3 = fmaf(E0, f3, 1.0f);
            const float p01 = t0 * t1, p23 = t2 * t3;
            const float num = fmaf(t0 + t1, p23, (t2 + t3) * p01);
            acc0 = fmaf(num, __builtin_amdgcn_rcpf(p01 * p23), acc0);
        }
        {
            const float t0 = fmaf(E1, f0, 1.0f), t1 = fmaf(E1, f1, 1.0f);
            const float t2 = fmaf(E1, f2, 1.0f), t3 = fmaf(E1, f3, 1.0f);
            const float p01 = t0 * t1, p23 = t2 * t3;
            const float num = fmaf(t0 + t1, p23, (t2 + t3) * p01);
            acc1 = fmaf(num, __builtin_amdgcn_rcpf(p01 * p23), acc1);
        }
    }
    if (hasRow2) {
        #pragma unroll 2
        for (int q = 0; q < nq; ++q) {
            const float f0 = F_s[(4 * q + 0) * H + h];
            const float f1 = F_s[(4 * q + 1) * H + h];
            const float f2 = F_s[(4 * q + 2) * H + h];
            const float f3 = F_s[(4 * q + 3) * H + h];
            const float t0 = fmaf(E2, f0, 1.0f), t1 = fmaf(E2, f1, 1.0f);
            const float t2 = fmaf(E2, f2, 1.0f), t3 = fmaf(E2, f3, 1.0f);
            const float p01 = t0 * t1, p23 = t2 * t3;
            const float num = fmaf(t0 + t1, p23, (t2 + t3) * p01);
            acc2 = fmaf(num, __builtin_amdgcn_rcpf(p01 * p23), acc2);
        }
    }

    // ---- epilogue: zero invalid original rows; scatter valid compacted ----
    const float rden = __builtin_amdgcn_rcpf((float)nvalid);
    float* ob = out + (size_t)b * (NV * H);
    #pragma unroll
    for (int it = 0; it < 3; ++it) {
        const int i = i0 + it * 16;                  // original row
        if (!((bits >> i) & 1ull)) ob[i * H + h] = 0.0f;
    }
    if (i0 < nvalid)        ob[validIdx[i0] * H + h]      = acc0 * rden;
    if (i0 + 16 < nvalid)   ob[validIdx[i0 + 16] * H + h] = acc1 * rden;
    if (hasRow2)            ob[validIdx[i0 + 32] * H + h] = acc2 * rden;
}

extern "C" void kernel_launch(void* const* d_in, const int* in_sizes, int n_in,
                              void* d_out, int out_size, void* d_ws, size_t ws_size,
                              hipStream_t stream) {
    const float* z    = (const float*)d_in[0];
    const float* Wc   = (const float*)d_in[1];
    const float* bc   = (const float*)d_in[2];
    const float* Wy   = (const float*)d_in[3];
    const float* by   = (const float*)d_in[4];
    const int*   mask = (const int*)d_in[5];
    float* out = (float*)d_out;

    const int ngraph = in_sizes[0] / (NV * H);   // 512
    OptLinker_attn_kernel<<<ngraph, BLOCK, 0, stream>>>(z, Wc, bc, Wy, by, mask, out);
}

// Round 6
// 11.386 us; speedup vs baseline: 1.6596x; 1.6596x over previous
//
#include <hip/hip_runtime.h>

// out[b,i,h] = m_i * (1/denom_b) * sum_{j valid} sigmoid(zc[b,i,h] + zy[b,j,h])
// zc = z@Wc^T+bc, zy = z@Wy^T+by.
// sigmoid(a+b) = 1/(1+e^{-a}e^{-b}); E=e^{-zc} (regs), F=e^{-zy} (LDS).
// Invalid j: F=1e8 sentinel -> contribution ~1e-8; stage B is a FIXED
// fully-unrolled 48-trip loop (compile-time LDS offsets -> compiler batches
// ds_reads; runtime trip counts regressed 1.7x in round 5).
// 4-way rational: 1/t0+1/t1+1/t2+1/t3 = (sum triple prods)/(t0t1t2t3) -> 1 rcp/4j.
// BLOCK=768 + launch_bounds(768,6): 24 waves/CU (grid 512 allows 2 blocks/CU;
// 512-thread blocks capped at 16 waves/CU). VGPR<=85 enabled by TWO-PASS
// stage A: only one W matrix row (32 VGPR) resident at a time.

#define LOG2E 1.4426950408889634f

constexpr int NV = 48;
constexpr int H  = 32;
constexpr int BLOCK = 768;      // 12 waves; thread = (i0 in 0..23, h in 0..31)
constexpr int WPAD = 36;        // padded W row stride (floats), 16B-aligned rows
constexpr float F_INV = 1.0e8f; // sentinel for invalid j

__global__ __launch_bounds__(BLOCK, 6)
void OptLinker_attn_kernel(const float* __restrict__ z,
                           const float* __restrict__ Wc,
                           const float* __restrict__ bc,
                           const float* __restrict__ Wy,
                           const float* __restrict__ by,
                           const int*   __restrict__ mask,
                           float* __restrict__ out)
{
    __shared__ float z_s[NV * H];       // 6 KB
    __shared__ float F_s[NV * H];       // 6 KB  e^{-zy[j,h]} (or sentinel)
    __shared__ float wc_s[H * WPAD];    // 4.5 KB
    __shared__ float wy_s[H * WPAD];    // 4.5 KB

    const int b   = blockIdx.x;
    const int tid = threadIdx.x;
    const int h   = tid & 31;           // lane's H column
    const int i0  = tid >> 5;           // 0..23; rows i0, i0+24

    // ---- mask + biases prefetch (longest dep chains first) ----
    const int lane = tid & 63;
    const int mv = (lane < NV) ? mask[b * NV + lane] : 0;
    const float bcv = bc[h], byv = by[h];

    // ---- z tile -> LDS (float4, coalesced; 384 float4) ----
    const float4* zb4 = (const float4*)(z + (size_t)b * (NV * H));
    if (tid < (NV * H) / 4) ((float4*)z_s)[tid] = zb4[tid];

    // ---- W -> LDS, coalesced, one float4 per thread (tid<512) ----
    if (tid < 512) {
        const int q = tid & 255;                    // float4 index within matrix
        const float4 v = (tid < 256) ? ((const float4*)Wc)[q]
                                     : ((const float4*)Wy)[q];
        float* dst = (tid < 256 ? wc_s : wy_s) + (q >> 3) * WPAD + (q & 7) * 4;
        *(float4*)dst = v;                          // 16B-aligned
    }

    const unsigned long long bits = __ballot(mv != 0);

    __syncthreads();   // z_s, W LDS ready

    const int r0 = i0, r1 = i0 + 24;
    const float4* zr0 = (const float4*)(z_s + r0 * H);
    const float4* zr1 = (const float4*)(z_s + r1 * H);

    // ---- stage A pass 1 (Wc): only wc row resident (32 VGPR) ----
    float E0, E1;
    {
        float4 w[8];
        const float* wr = wc_s + h * WPAD;
        #pragma unroll
        for (int q = 0; q < 8; ++q) w[q] = *(const float4*)(wr + q * 4);
        float a0 = bcv, a1 = bcv;
        #pragma unroll
        for (int q = 0; q < 8; ++q) {
            const float4 z0 = zr0[q], z1 = zr1[q];  // broadcast ds_read_b128
            a0 = fmaf(z0.x, w[q].x, a0); a0 = fmaf(z0.y, w[q].y, a0);
            a0 = fmaf(z0.z, w[q].z, a0); a0 = fmaf(z0.w, w[q].w, a0);
            a1 = fmaf(z1.x, w[q].x, a1); a1 = fmaf(z1.y, w[q].y, a1);
            a1 = fmaf(z1.z, w[q].z, a1); a1 = fmaf(z1.w, w[q].w, a1);
        }
        E0 = __builtin_amdgcn_exp2f(-a0 * LOG2E);   // e^{-zc}
        E1 = __builtin_amdgcn_exp2f(-a1 * LOG2E);
    }

    // ---- stage A pass 2 (Wy): wy row replaces wc row ----
    {
        float4 w[8];
        const float* wr = wy_s + h * WPAD;
        #pragma unroll
        for (int q = 0; q < 8; ++q) w[q] = *(const float4*)(wr + q * 4);
        float a0 = byv, a1 = byv;
        #pragma unroll
        for (int q = 0; q < 8; ++q) {
            const float4 z0 = zr0[q], z1 = zr1[q];
            a0 = fmaf(z0.x, w[q].x, a0); a0 = fmaf(z0.y, w[q].y, a0);
            a0 = fmaf(z0.z, w[q].z, a0); a0 = fmaf(z0.w, w[q].w, a0);
            a1 = fmaf(z1.x, w[q].x, a1); a1 = fmaf(z1.y, w[q].y, a1);
            a1 = fmaf(z1.z, w[q].z, a1); a1 = fmaf(z1.w, w[q].w, a1);
        }
        F_s[r0 * H + h] = ((bits >> r0) & 1ull)
                        ? __builtin_amdgcn_exp2f(-a0 * LOG2E) : F_INV;
        F_s[r1 * H + h] = ((bits >> r1) & 1ull)
                        ? __builtin_amdgcn_exp2f(-a1 * LOG2E) : F_INV;
    }

    __syncthreads();   // F_s ready

    // ---- stage B: fixed 48-trip loop, 4-way rational combine, 2 rows ----
    float acc0 = 0.f, acc1 = 0.f;
    #pragma unroll
    for (int j = 0; j < NV; j += 4) {
        const float f0 = F_s[(j + 0) * H + h];   // conflict-free broadcast
        const float f1 = F_s[(j + 1) * H + h];
        const float f2 = F_s[(j + 2) * H + h];
        const float f3 = F_s[(j + 3) * H + h];
        {
            const float t0 = fmaf(E0, f0, 1.0f), t1 = fmaf(E0, f1, 1.0f);
            const float t2 = fmaf(E0, f2, 1.0f), t3 = fmaf(E0, f3, 1.0f);
            const float p01 = t0 * t1, p23 = t2 * t3;
            const float num = fmaf(t0 + t1, p23, (t2 + t3) * p01);
            acc0 = fmaf(num, __builtin_amdgcn_rcpf(p01 * p23), acc0);
        }
        {
            const float t0 = fmaf(E1, f0, 1.0f), t1 = fmaf(E1, f1, 1.0f);
            const float t2 = fmaf(E1, f2, 1.0f), t3 = fmaf(E1, f3, 1.0f);
            const float p01 = t0 * t1, p23 = t2 * t3;
            const float num = fmaf(t0 + t1, p23, (t2 + t3) * p01);
            acc1 = fmaf(num, __builtin_amdgcn_rcpf(p01 * p23), acc1);
        }
    }

    // ---- epilogue ----
    const int nvalid = __popcll(bits);
    const float rden = __builtin_amdgcn_rcpf((float)nvalid);
    float* ob = out + (size_t)b * (NV * H);
    ob[r0 * H + h] = ((bits >> r0) & 1ull) ? acc0 * rden : 0.0f;
    ob[r1 * H + h] = ((bits >> r1) & 1ull) ? acc1 * rden : 0.0f;
}

extern "C" void kernel_launch(void* const* d_in, const int* in_sizes, int n_in,
                              void* d_out, int out_size, void* d_ws, size_t ws_size,
                              hipStream_t stream) {
    const float* z    = (const float*)d_in[0];
    const float* Wc   = (const float*)d_in[1];
    const float* bc   = (const float*)d_in[2];
    const float* Wy   = (const float*)d_in[3];
    const float* by   = (const float*)d_in[4];
    const int*   mask = (const int*)d_in[5];
    float* out = (float*)d_out;

    const int ngraph = in_sizes[0] / (NV * H);   // 512
    OptLinker_attn_kernel<<<ngraph, BLOCK, 0, stream>>>(z, Wc, bc, Wy, by, mask, out);
}

// Round 7
// 11.140 us; speedup vs baseline: 1.6962x; 1.0220x over previous
//
#include <hip/hip_runtime.h>

// out[b,i,h] = m_i * (1/denom_b) * sum_{j valid} sigmoid(zc[b,i,h] + zy[b,j,h])
// zc = z@Wc^T+bc, zy = z@Wy^T+by.
// sigmoid(a+b) = 1/(1+e^{-a}e^{-b}); E=e^{-zc} (regs), F=e^{-zy} (LDS).
// Invalid j: F=1e8 sentinel -> contribution ~1e-8; stage B is a FIXED
// fully-unrolled 48-trip loop. 4-way rational combine -> 1 v_rcp per 4 j per row.
// PACKED f32 (v_pk_fma_f32 etc. via ext_vector_type(2)):
//   stage A packs the K dimension (z/W rows are contiguous float2 pairs),
//   stage B packs the thread's TWO OUTPUT ROWS into one v2f (E2=(E0,E1)).
// ~35% fewer VALU instructions; numerics identical (per-component IEEE fma).

#define LOG2E 1.4426950408889634f

typedef float v2f __attribute__((ext_vector_type(2)));

constexpr int NV = 48;
constexpr int H  = 32;
constexpr int BLOCK = 768;      // 12 waves; thread = (i0 in 0..23, h in 0..31)
constexpr int WPAD = 36;        // padded W row stride (floats), 16B-aligned rows
constexpr float F_INV = 1.0e8f; // sentinel for invalid j

__global__ __launch_bounds__(BLOCK, 6)
void OptLinker_attn_kernel(const float* __restrict__ z,
                           const float* __restrict__ Wc,
                           const float* __restrict__ bc,
                           const float* __restrict__ Wy,
                           const float* __restrict__ by,
                           const int*   __restrict__ mask,
                           float* __restrict__ out)
{
    __shared__ float z_s[NV * H];       // 6 KB
    __shared__ float F_s[NV * H];       // 6 KB  e^{-zy[j,h]} (or sentinel)
    __shared__ float wc_s[H * WPAD];    // 4.5 KB
    __shared__ float wy_s[H * WPAD];    // 4.5 KB

    const int b   = blockIdx.x;
    const int tid = threadIdx.x;
    const int h   = tid & 31;           // lane's H column
    const int i0  = tid >> 5;           // 0..23; rows i0, i0+24

    // ---- mask + biases prefetch (longest dep chains first) ----
    const int lane = tid & 63;
    const int mv = (lane < NV) ? mask[b * NV + lane] : 0;
    const float bcv = bc[h], byv = by[h];

    // ---- z tile -> LDS (float4, coalesced; 384 float4) ----
    const float4* zb4 = (const float4*)(z + (size_t)b * (NV * H));
    if (tid < (NV * H) / 4) ((float4*)z_s)[tid] = zb4[tid];

    // ---- W -> LDS, coalesced, one float4 per thread (tid<512) ----
    if (tid < 512) {
        const int q = tid & 255;                    // float4 index within matrix
        const float4 v = (tid < 256) ? ((const float4*)Wc)[q]
                                     : ((const float4*)Wy)[q];
        float* dst = (tid < 256 ? wc_s : wy_s) + (q >> 3) * WPAD + (q & 7) * 4;
        *(float4*)dst = v;                          // 16B-aligned
    }

    const unsigned long long bits = __ballot(mv != 0);

    __syncthreads();   // z_s, W LDS ready

    const int r0 = i0, r1 = i0 + 24;
    const float4* zr0 = (const float4*)(z_s + r0 * H);
    const float4* zr1 = (const float4*)(z_s + r1 * H);

    // ---- stage A pass 1 (Wc): packed-K dual-row matvec ----
    float E0, E1;
    {
        float4 w[8];
        const float* wr = wc_s + h * WPAD;
        #pragma unroll
        for (int q = 0; q < 8; ++q) w[q] = *(const float4*)(wr + q * 4);
        v2f a0 = {0.f, 0.f}, a1 = {0.f, 0.f};
        #pragma unroll
        for (int q = 0; q < 8; ++q) {
            const float4 z0 = zr0[q], z1 = zr1[q];  // broadcast ds_read_b128
            const v2f wlo = {w[q].x, w[q].y}, whi = {w[q].z, w[q].w};
            a0 = __builtin_elementwise_fma((v2f){z0.x, z0.y}, wlo, a0);
            a0 = __builtin_elementwise_fma((v2f){z0.z, z0.w}, whi, a0);
            a1 = __builtin_elementwise_fma((v2f){z1.x, z1.y}, wlo, a1);
            a1 = __builtin_elementwise_fma((v2f){z1.z, z1.w}, whi, a1);
        }
        E0 = __builtin_amdgcn_exp2f(-(a0.x + a0.y + bcv) * LOG2E);  // e^{-zc}
        E1 = __builtin_amdgcn_exp2f(-(a1.x + a1.y + bcv) * LOG2E);
    }

    // ---- stage A pass 2 (Wy): wy row replaces wc row ----
    {
        float4 w[8];
        const float* wr = wy_s + h * WPAD;
        #pragma unroll
        for (int q = 0; q < 8; ++q) w[q] = *(const float4*)(wr + q * 4);
        v2f a0 = {0.f, 0.f}, a1 = {0.f, 0.f};
        #pragma unroll
        for (int q = 0; q < 8; ++q) {
            const float4 z0 = zr0[q], z1 = zr1[q];
            const v2f wlo = {w[q].x, w[q].y}, whi = {w[q].z, w[q].w};
            a0 = __builtin_elementwise_fma((v2f){z0.x, z0.y}, wlo, a0);
            a0 = __builtin_elementwise_fma((v2f){z0.z, z0.w}, whi, a0);
            a1 = __builtin_elementwise_fma((v2f){z1.x, z1.y}, wlo, a1);
            a1 = __builtin_elementwise_fma((v2f){z1.z, z1.w}, whi, a1);
        }
        F_s[r0 * H + h] = ((bits >> r0) & 1ull)
            ? __builtin_amdgcn_exp2f(-(a0.x + a0.y + byv) * LOG2E) : F_INV;
        F_s[r1 * H + h] = ((bits >> r1) & 1ull)
            ? __builtin_amdgcn_exp2f(-(a1.x + a1.y + byv) * LOG2E) : F_INV;
    }

    __syncthreads();   // F_s ready

    // ---- stage B: fixed 48-trip loop, rows packed as v2f lanes ----
    const v2f E2  = {E0, E1};
    const v2f one = {1.f, 1.f};
    v2f acc2 = {0.f, 0.f};
    #pragma unroll
    for (int j = 0; j < NV; j += 4) {
        const float f0 = F_s[(j + 0) * H + h];   // conflict-free broadcast
        const float f1 = F_s[(j + 1) * H + h];
        const float f2 = F_s[(j + 2) * H + h];
        const float f3 = F_s[(j + 3) * H + h];
        const v2f t0 = __builtin_elementwise_fma(E2, (v2f){f0, f0}, one);
        const v2f t1 = __builtin_elementwise_fma(E2, (v2f){f1, f1}, one);
        const v2f t2 = __builtin_elementwise_fma(E2, (v2f){f2, f2}, one);
        const v2f t3 = __builtin_elementwise_fma(E2, (v2f){f3, f3}, one);
        const v2f p01 = t0 * t1, p23 = t2 * t3;
        const v2f num = __builtin_elementwise_fma(t0 + t1, p23, (t2 + t3) * p01);
        const v2f den = p01 * p23;
        v2f r;
        r.x = __builtin_amdgcn_rcpf(den.x);
        r.y = __builtin_amdgcn_rcpf(den.y);
        acc2 = __builtin_elementwise_fma(num, r, acc2);
    }

    // ---- epilogue ----
    const int nvalid = __popcll(bits);
    const float rden = __builtin_amdgcn_rcpf((float)nvalid);
    float* ob = out + (size_t)b * (NV * H);
    ob[r0 * H + h] = ((bits >> r0) & 1ull) ? acc2.x * rden : 0.0f;
    ob[r1 * H + h] = ((bits >> r1) & 1ull) ? acc2.y * rden : 0.0f;
}

extern "C" void kernel_launch(void* const* d_in, const int* in_sizes, int n_in,
                              void* d_out, int out_size, void* d_ws, size_t ws_size,
                              hipStream_t stream) {
    const float* z    = (const float*)d_in[0];
    const float* Wc   = (const float*)d_in[1];
    const float* bc   = (const float*)d_in[2];
    const float* Wy   = (const float*)d_in[3];
    const float* by   = (const float*)d_in[4];
    const int*   mask = (const int*)d_in[5];
    float* out = (float*)d_out;

    const int ngraph = in_sizes[0] / (NV * H);   // 512
    OptLinker_attn_kernel<<<ngraph, BLOCK, 0, stream>>>(z, Wc, bc, Wy, by, mask, out);
}